// Round 11
// baseline (637.683 us; speedup 1.0000x reference)
//
#include <hip/hip_runtime.h>
#include <hip/hip_bf16.h>
#include <hip/hip_cooperative_groups.h>

namespace cg = cooperative_groups;

// Problem constants (fixed by setup_inputs)
#define NG      100
#define NPG     500
#define EPG     4000
#define HID     128
#define NNODES  (NG*NPG)     // 50000
#define NE      (NG*EPG)     // 400000
#define KSEL    2000         // ceil(0.5*4000)
#define NB_SCAN ((NNODES + 255) / 256)   // 196

#define MAXB    1024         // boundary-list capacity per graph (expect ~140)
#define NRC     8            // repair chunks per graph (MAXB/128)
#define RJT     8            // repair j-tiles (512/64)
#define DELTA   0.03125f     // screening margin (~2x observed bf16 att max err)

// Output layout (floats, concatenated in reference return order)
#define O_ATT   0
#define O_CEW   (NE)
#define O_SEW   (2*NE)
#define O_MASK  (3*NE)
#define O_CEI   (4*NE)            // 2*NE entries: new_row then new_col
#define O_NMASK (6*NE)            // NNODES entries
#define O_CX    (6*NE + NNODES)   // NNODES*HID entries

typedef __attribute__((ext_vector_type(8))) short  short8;
typedef __attribute__((ext_vector_type(8))) __bf16 bf16x8;
typedef __attribute__((ext_vector_type(4))) float  f32x4;

#define MFMA16(a,b,c) __builtin_amdgcn_mfma_f32_16x16x32_bf16( \
    __builtin_bit_cast(bf16x8,(a)), __builtin_bit_cast(bf16x8,(b)), (c), 0, 0, 0)

#define GLOAD_LDS16(g, l) __builtin_amdgcn_global_load_lds( \
    (const __attribute__((address_space(1))) unsigned int*)(g), \
    (__attribute__((address_space(3)))       unsigned int*)(l), 16, 0, 0)

__device__ __forceinline__ unsigned short tobf(float x) {
    __hip_bfloat16 hb = __float2bfloat16(x);
    return *(unsigned short*)&hb;
}

// ---------------- fused preprocessing ----------------
#define PREP_TOBF 6250
#define PREP_PACK 512
#define PREP_DEG  49
#define PREP_GRID (PREP_TOBF + PREP_PACK + PREP_DEG + 1)

__global__ __launch_bounds__(256)
void prep_kernel(const float* __restrict__ emb, const float* __restrict__ W1,
                 unsigned short* __restrict__ eb, unsigned short* __restrict__ ph,
                 float* __restrict__ deg, int* __restrict__ bcnt)
{
    const int blk = blockIdx.x;
    const int t   = threadIdx.x;
    if (blk < PREP_TOBF) {
        int i = blk * 256 + t;                       // float4 index, 1.6M total
        float4 v = ((const float4*)emb)[i];
        ushort4 h;
        h.x = tobf(v.x); h.y = tobf(v.y); h.z = tobf(v.z); h.w = tobf(v.w);
        ((ushort4*)eb)[i] = h;
    } else if (blk < PREP_TOBF + PREP_PACK) {
        int idx  = (blk - PREP_TOBF) * 256 + t;      // 131072 total
        int i    = idx & 7;
        int lane = (idx >> 3) & 63;
        int g    = idx >> 9;
        int jsub = g & 3;
        int rem  = g >> 2;
        int jo   = rem & 7;
        int kc   = rem >> 3;                         // 0..7
        int j = jo * 64 + jsub * 16 + (lane & 15);
        int k = kc * 32 + (lane >> 4) * 8 + i;
        ph[idx] = tobf(W1[k * 512 + j]);
    } else if (blk < PREP_TOBF + PREP_PACK + PREP_DEG) {
        int i4 = (blk - PREP_TOBF - PREP_PACK) * 256 + t;
        if (i4 < NNODES / 4) ((float4*)deg)[i4] = make_float4(0.f, 0.f, 0.f, 0.f);
    } else {
        if (t < NG) bcnt[t] = 0;
    }
}

// ---------------- screening GEMM: bf16 MFMA, double-buffered B ------------
// v11 == v6 (best measured: 120.2-120.7 us, VGPR 116, MfmaUtil 37%).
// 16 segments of 32 j-cols, 2 x 16 KB LDS buffers, 64 edges/wave (4 mt).
// Evidence: allocator budget ~116 VGPR, never holds A resident (R3/R4/R7);
// min-waves hints spill (R2/R5); mt=2 and K-split variants regress (R8/R9);
// occupancy not the limiter (R8). MFMA floor ~50us; the rest is A-remat
// L2 traffic, un-fixable at HIP source level.
__global__ __launch_bounds__(256)
void att5_kernel(const unsigned short* __restrict__ embb,
                 const unsigned short* __restrict__ w1p,
                 const int* __restrict__ ei,
                 const float* __restrict__ b1,
                 const float* __restrict__ W2,
                 const float* __restrict__ b2,
                 float* __restrict__ out)
{
    // 2 buffers x 16 chunks x 512 bf16; chunk c2 = kc*2 + jsub2, kc in [0,8)
    __shared__ __align__(16) unsigned short ldsB[16384];   // 32 KB

    const int t    = threadIdx.x;
    const int w    = t >> 6;        // wave 0..3
    const int lane = t & 63;
    const int r16  = lane & 15;
    const int quad = lane >> 4;

    const int e_base = blockIdx.x * 256 + w * 64;
    const char* eb = (const char*)embb;

    f32x4 A[4][8];
#pragma unroll
    for (int mt = 0; mt < 4; ++mt) {
        int e = min(e_base + mt * 16 + r16, NE - 1);
        const char* sp = eb + (ei[e] << 8);        // 256 B per node row
        const char* dp = eb + (ei[NE + e] << 8);
#pragma unroll
        for (int k4 = 0; k4 < 4; ++k4) {
            A[mt][k4]     = *(const f32x4*)(sp + k4 * 64 + quad * 16);
            A[mt][k4 + 4] = *(const f32x4*)(dp + k4 * 64 + quad * 16);
        }
    }

    float attP[4][4];
#pragma unroll
    for (int mt = 0; mt < 4; ++mt)
#pragma unroll
        for (int rg = 0; rg < 4; ++rg) attP[mt][rg] = 0.0f;

#define STAGE(s_, buf_)                                                      \
    {                                                                        \
        _Pragma("unroll")                                                    \
        for (int cc = 0; cc < 4; ++cc) {                                     \
            int c2   = w * 4 + cc;                                           \
            int kc   = c2 >> 1;                                              \
            int jsub = ((s_) & 1) * 2 + (c2 & 1);                            \
            int jo   = (s_) >> 1;                                            \
            int g    = (kc * 8 + jo) * 4 + jsub;                             \
            GLOAD_LDS16(w1p + g * 512 + lane * 8,                            \
                        ldsB + (buf_) * 8192 + c2 * 512);                    \
        }                                                                    \
    }

    STAGE(0, 0);
    __syncthreads();

    for (int s = 0; s < 16; ++s) {
        const int cur = s & 1;
        if (s < 15) STAGE(s + 1, cur ^ 1);   // prefetch next segment early

#pragma unroll
        for (int jsub2 = 0; jsub2 < 2; ++jsub2) {
            f32x4 acc[4];   // one jsub at a time: 16 VGPRs
#pragma unroll
            for (int mt = 0; mt < 4; ++mt) acc[mt] = f32x4{};

#pragma unroll
            for (int kc = 0; kc < 8; ++kc) {
                short8 B = *(const short8*)(ldsB + cur * 8192 +
                                            (kc * 2 + jsub2) * 512 + lane * 8);
#pragma unroll
                for (int mt = 0; mt < 4; ++mt)
                    acc[mt] = MFMA16(A[mt][kc], B, acc[mt]);
            }

            const int j = s * 32 + jsub2 * 16 + r16;
            const float b1v = b1[j], w2v = W2[j];
#pragma unroll
            for (int mt = 0; mt < 4; ++mt)
#pragma unroll
                for (int rg = 0; rg < 4; ++rg)
                    attP[mt][rg] += fmaxf(acc[mt][rg] + b1v, 0.0f) * w2v;
        }
        __syncthreads();   // prefetch landed + all reads of cur done
    }
#undef STAGE

#pragma unroll
    for (int mt = 0; mt < 4; ++mt)
#pragma unroll
        for (int rg = 0; rg < 4; ++rg) {
            float v = attP[mt][rg];
#pragma unroll
            for (int msk = 1; msk <= 8; msk <<= 1) v += __shfl_xor(v, msk, 64);
            attP[mt][rg] = v;
        }

    const float bias2 = b2[0];
    if (r16 < 4) {
#pragma unroll
        for (int mt = 0; mt < 4; ++mt) {
            const int row = quad * 4 + r16;    // C/D row = (lane>>4)*4 + reg
            const int e   = e_base + mt * 16 + row;
            if (e < NE) out[O_ATT + e] = attP[mt][r16] + bias2;
        }
    }
}

// ---------------- per-graph top-k screening ----------------
__device__ __forceinline__ unsigned enc_key(float f) {
    unsigned u = __float_as_uint(f);
    return (u & 0x80000000u) ? ~u : (u | 0x80000000u);
}
__device__ __forceinline__ float dec_key(unsigned k) {
    unsigned u = (k & 0x80000000u) ? (k ^ 0x80000000u) : ~k;
    return __uint_as_float(u);
}

__device__ __forceinline__ int wave_sum(int c) {
#pragma unroll
    for (int m = 1; m <= 32; m <<= 1) c += __shfl_xor(c, m, 64);
    return c;
}

__global__ __launch_bounds__(256)
void topk4_kernel(const int* __restrict__ ei, float* __restrict__ out,
                  float* __restrict__ deg, int* __restrict__ bcnt,
                  int* __restrict__ need, int* __restrict__ blist)
{
    __shared__ int cnt;

    const int g  = blockIdx.x;
    const int t  = threadIdx.x;
    const int e0 = g * EPG;
    const int cbase = t * 16;            // blocked chunk, threads 0..249 active
    const bool act = (t < 250);

    unsigned kreg[16];
    if (act) {
#pragma unroll
        for (int q4 = 0; q4 < 4; ++q4) {
            float4 v = *(const float4*)&out[O_ATT + e0 + cbase + q4 * 4];
            kreg[q4 * 4 + 0] = enc_key(v.x);
            kreg[q4 * 4 + 1] = enc_key(v.y);
            kreg[q4 * 4 + 2] = enc_key(v.z);
            kreg[q4 * 4 + 3] = enc_key(v.w);
        }
    }

    unsigned lo = 0u, hi = 0xFFFFFFFFu;
    while (lo < hi) {
        unsigned mid = lo + ((hi - lo) >> 1) + 1u;
        if (t == 0) cnt = 0;
        __syncthreads();
        int c = 0;
        if (act) {
#pragma unroll
            for (int q = 0; q < 16; ++q) c += (kreg[q] >= mid) ? 1 : 0;
        }
        c = wave_sum(c);
        if ((t & 63) == 0 && c) atomicAdd(&cnt, c);
        __syncthreads();
        int f = cnt;
        if (f >= KSEL) lo = mid; else hi = mid - 1u;
        __syncthreads();
    }
    const unsigned K = lo;
    const float v = dec_key(K);
    const unsigned khi = enc_key(v + DELTA);
    const unsigned klo = enc_key(v - DELTA);

    if (t == 0) cnt = 0;
    __syncthreads();
    {
        int c = 0;
        if (act) {
#pragma unroll
            for (int q = 0; q < 16; ++q) c += (kreg[q] > khi) ? 1 : 0;
        }
        c = wave_sum(c);
        if ((t & 63) == 0 && c) atomicAdd(&cnt, c);
    }
    __syncthreads();
    if (t == 0) need[g] = KSEL - cnt;

    if (act) {
#pragma unroll
        for (int q = 0; q < 16; ++q) {
            unsigned kk = kreg[q];
            int ge = e0 + cbase + q;
            float a = dec_key(kk);
            if (kk > khi) {
                out[O_CEW + ge]  = a;
                out[O_SEW + ge]  = 0.0f;
                out[O_MASK + ge] = 1.0f;
                atomicAdd(&deg[ei[ge]], 1.0f);
                atomicAdd(&deg[ei[NE + ge]], 1.0f);
            } else if (kk < klo) {
                out[O_CEW + ge]  = 0.0f;
                out[O_SEW + ge]  = a;
                out[O_MASK + ge] = 0.0f;
            } else {
                int p = atomicAdd(&bcnt[g], 1);
                if (p < MAXB) blist[g * MAXB + p] = ge;
            }
        }
    }
}

// ---------------- exact fp32 recompute of boundary edges ----------------
#define TE_  128
#define PADX 132
#define PADW 68

__global__ __launch_bounds__(256)
void repair_kernel(const float* __restrict__ emb, const int* __restrict__ ei,
                   const float* __restrict__ W1, const float* __restrict__ b1,
                   const float* __restrict__ W2,
                   const int* __restrict__ bcnt, const int* __restrict__ blist,
                   float* __restrict__ attx8)
{
    const int blk = blockIdx.x;
    const int ch  = blk / (NG * RJT);          // 0..NRC-1
    const int rem = blk - ch * (NG * RJT);
    const int g   = rem >> 3;                  // /RJT
    const int jt  = rem & 7;
    const int bc  = min(bcnt[g], MAXB);
    if (ch * 128 >= bc) return;
    const int live = min(bc - ch * 128, TE_);  // 1..128 real edges this chunk

    __shared__ __align__(16) float Xs[32 * PADX];   // 16.9 KB
    __shared__ __align__(16) float Ws[32 * PADW];   //  8.7 KB
    __shared__ int sidx[TE_], cidx[TE_];

    const int t = threadIdx.x;
    if (t < TE_) {
        int lid = ch * 128 + t;
        int lc  = min(lid, bc - 1);
        int e   = blist[g * MAXB + lc];
        sidx[t] = ei[e];
        cidx[t] = ei[NE + e];
    }
    __syncthreads();

    const int te = t & 15;     // edge group: edges te*8..te*8+7
    const int tj = t >> 4;     // j group: j jt*64 + tj*4..+3
    const bool alive = (te * 8 < live);

    float acc[8][4];
#pragma unroll
    for (int a = 0; a < 8; ++a)
#pragma unroll
        for (int b = 0; b < 4; ++b) acc[a][b] = 0.0f;

    for (int kt = 0; kt < 8; ++kt) {
        __syncthreads();
#pragma unroll
        for (int i = 0; i < 4; ++i) {
            int flat = i * 256 + t;           // 0..1023
            int e  = flat >> 3;
            if (e < live) {
                int k4 = flat & 7;
                int k  = kt * 32 + k4 * 4;
                const float* src;
                if (k < HID) src = emb + (long)sidx[e] * HID + k;
                else         src = emb + (long)cidx[e] * HID + (k - HID);
                float4 v = *(const float4*)src;
                int kl = k4 * 4;
                Xs[(kl + 0) * PADX + e] = v.x;
                Xs[(kl + 1) * PADX + e] = v.y;
                Xs[(kl + 2) * PADX + e] = v.z;
                Xs[(kl + 3) * PADX + e] = v.w;
            }
        }
#pragma unroll
        for (int i = 0; i < 2; ++i) {
            int flat = i * 256 + t;           // 0..511
            int kl = flat >> 4;
            int j4 = flat & 15;
            float4 v = *(const float4*)&W1[(kt * 32 + kl) * 512 + jt * 64 + j4 * 4];
            *(float4*)&Ws[kl * PADW + j4 * 4] = v;
        }
        __syncthreads();

        if (alive) {
#pragma unroll 4
            for (int kl = 0; kl < 32; ++kl) {
                float4 xa = *(const float4*)&Xs[kl * PADX + te * 8];
                float4 xb = *(const float4*)&Xs[kl * PADX + te * 8 + 4];
                float4 wa = *(const float4*)&Ws[kl * PADW + tj * 4];
                float xv[8] = {xa.x, xa.y, xa.z, xa.w, xb.x, xb.y, xb.z, xb.w};
                float wv[4] = {wa.x, wa.y, wa.z, wa.w};
#pragma unroll
                for (int a = 0; a < 8; ++a)
#pragma unroll
                    for (int b = 0; b < 4; ++b)
                        acc[a][b] = fmaf(xv[a], wv[b], acc[a][b]);
            }
        }
    }

    __syncthreads();
    float* red = Xs;   // 16*136 = 2176 floats, fits
    if (alive) {
        const int jb = jt * 64 + tj * 4;
        float4 b1a = *(const float4*)&b1[jb];
        float4 w2a = *(const float4*)&W2[jb];
        float bv[4] = {b1a.x, b1a.y, b1a.z, b1a.w};
        float wv[4] = {w2a.x, w2a.y, w2a.z, w2a.w};
#pragma unroll
        for (int a = 0; a < 8; ++a) {
            float s = 0.0f;
#pragma unroll
            for (int b = 0; b < 4; ++b)
                s = fmaf(fmaxf(acc[a][b] + bv[b], 0.0f), wv[b], s);
            red[tj * 136 + te * 8 + a] = s;
        }
    }
    __syncthreads();
    if (t < TE_ && t < live) {
        float s = 0.0f;
#pragma unroll
        for (int q = 0; q < 16; ++q) s += red[q * 136 + t];
        attx8[(g * MAXB + ch * 128 + t) * RJT + jt] = s;
    }
}

// ---------------- fused tail: select + scanA + scanC + final --------------
// v11: one cooperative kernel, 3 grid.sync()s replace 3 kernel launches
// (R9->R10 showed ~4us per removed launch; this measures whether the
// ~120us unattributed remainder is launch/tail overhead or kernel-internal).
// Phase bodies are verbatim from the R10 kernels, grid-strided.
#define TAIL_GRID 1024

__global__ __launch_bounds__(256)
void tail_kernel(const int* __restrict__ ei, const int* __restrict__ bcnt,
                 const int* __restrict__ need, const int* __restrict__ blist,
                 const float* __restrict__ attx8, const float* __restrict__ b2,
                 float* __restrict__ out, float* __restrict__ deg,
                 int* __restrict__ partials, int* __restrict__ newid,
                 const float* __restrict__ emb)
{
    cg::grid_group grid = cg::this_grid();
    const int t = threadIdx.x;

    __shared__ float sa[MAXB];
    __shared__ int   si[MAXB];

    // ---- P1: select (100 graphs) ----
    for (int g = blockIdx.x; g < NG; g += gridDim.x) {
        const int b = min(bcnt[g], MAXB);
        const int n = need[g];
        const float bias2 = b2[0];

        for (int i = t; i < b; i += 256) {
            float s = bias2;
#pragma unroll
            for (int jt = 0; jt < RJT; ++jt)
                s += attx8[(g * MAXB + i) * RJT + jt];
            sa[i] = s;
            si[i] = blist[g * MAXB + i];
        }
        __syncthreads();

        for (int i = t; i < b; i += 256) {
            float ai = sa[i];
            int   ii = si[i];
            int rank = 0;
            for (int j = 0; j < b; ++j)
                rank += (sa[j] > ai || (sa[j] == ai && si[j] < ii)) ? 1 : 0;
            bool flag = rank < n;
            out[O_CEW + ii]  = flag ? ai : 0.0f;
            out[O_SEW + ii]  = flag ? 0.0f : ai;
            out[O_MASK + ii] = flag ? 1.0f : 0.0f;
            if (flag) {
                atomicAdd(&deg[ei[ii]], 1.0f);
                atomicAdd(&deg[ei[NE + ii]], 1.0f);
            }
        }
        __syncthreads();   // sa/si reuse safety across grid-stride iterations
    }

    grid.sync();   // all deg atomics visible

    // ---- P2: scanA (196 chunks) ----
    int* s4 = si;   // reuse LDS
    for (int vb = blockIdx.x; vb < NB_SCAN; vb += gridDim.x) {
        int n = vb * 256 + t;
        int m = (n < NNODES && deg[n] > 0.5f) ? 1 : 0;
        s4[t] = m;
        __syncthreads();
        for (int off = 128; off > 0; off >>= 1) {
            if (t < off) s4[t] += s4[t + off];
            __syncthreads();
        }
        if (t == 0) partials[vb] = s4[0];
        __syncthreads();
    }

    grid.sync();   // all partials visible

    // ---- P3: scanC with inline prefix-of-partials (196 chunks) ----
    int* p4 = (int*)sa;   // reuse LDS
    for (int vb = blockIdx.x; vb < NB_SCAN; vb += gridDim.x) {
        // exclusive prefix for chunk vb: sum of partials[0..vb)
        p4[t] = (t < NB_SCAN && t < vb) ? partials[t] : 0;
        __syncthreads();
        for (int off = 128; off > 0; off >>= 1) {
            if (t < off) p4[t] += p4[t + off];
            __syncthreads();
        }
        const int ex_b = p4[0];
        __syncthreads();

        int n = vb * 256 + t;
        int m = (n < NNODES && deg[n] > 0.5f) ? 1 : 0;
        s4[t] = m;
        __syncthreads();
        for (int off = 1; off < 256; off <<= 1) {
            int x = (t >= off) ? s4[t - off] : 0;
            __syncthreads();
            s4[t] += x;
            __syncthreads();
        }
        if (n < NNODES) {
            newid[n] = ex_b + s4[t] - 1;      // cumsum(mask)-1
            deg[n]   = m ? 1.0f : 0.0f;       // finalize node_mask output
        }
        __syncthreads();
    }

    grid.sync();   // newid + node_mask final

    // ---- P4: final (edge relabel + causal_x) ----
#define FIN_EDGE 1563
#define FIN_GRID (FIN_EDGE + 6250)
    for (int vb = blockIdx.x; vb < FIN_GRID; vb += gridDim.x) {
        if (vb < FIN_EDGE) {
            int e = vb * 256 + t;
            if (e < NE) {
                bool flag = out[O_MASK + e] > 0.5f;
                int row = ei[e];
                int col = ei[NE + e];
                out[O_CEI + e]      = flag ? (float)newid[row] : -1.0f;
                out[O_CEI + NE + e] = flag ? (float)newid[col] : -1.0f;
            }
        } else {
            int i4 = (vb - FIN_EDGE) * 256 + t;            // float4 index
            if (i4 < NNODES * HID / 4) {
                int n = i4 >> 5;                           // 32 float4 per node
                float4 v = ((const float4*)emb)[i4];
                if (!(deg[n] > 0.5f)) v = make_float4(0.0f, 0.0f, 0.0f, 0.0f);
                ((float4*)(out + O_CX))[i4] = v;
            }
        }
    }
}

extern "C" void kernel_launch(void* const* d_in, const int* in_sizes, int n_in,
                              void* d_out, int out_size, void* d_ws, size_t ws_size,
                              hipStream_t stream)
{
    const float* emb = (const float*)d_in[0];
    const int*   ei  = (const int*)d_in[1];
    // d_in[2] = node_batch (implied by edge layout; unused)
    const float* W1  = (const float*)d_in[3];
    const float* b1  = (const float*)d_in[4];
    const float* W2  = (const float*)d_in[5];
    const float* b2  = (const float*)d_in[6];
    float* out = (float*)d_out;

    char* wsb = (char*)d_ws;
    int*   newid    = (int*)wsb;                          // 200000 B
    int*   partials = (int*)(wsb + 200704);
    int*   bcnt     = (int*)(wsb + 201728);               // NG ints
    int*   need     = (int*)(wsb + 202752);               // NG ints
    int*   blist    = (int*)(wsb + 203776);               // NG*MAXB ints (400 KB)
    float* attx8    = (float*)(wsb + 203776 + NG*MAXB*4); // NG*MAXB*RJT floats (3.3 MB)
    unsigned short* embb = (unsigned short*)(wsb + 203776 + NG*MAXB*4 + NG*MAXB*RJT*4);
    unsigned short* w1p  = embb + NNODES * HID;           // 131072 bf16
    float* deg = out + O_NMASK;                           // node_mask region as deg accum

    prep_kernel<<<PREP_GRID, 256, 0, stream>>>(emb, W1, embb, w1p, deg, bcnt);
    att5_kernel<<<(NE + 255) / 256, 256, 0, stream>>>(embb, w1p, ei, b1, W2, b2, out);
    topk4_kernel<<<NG, 256, 0, stream>>>(ei, out, deg, bcnt, need, blist);
    repair_kernel<<<NG * NRC * RJT, 256, 0, stream>>>(emb, ei, W1, b1, W2,
                                                      bcnt, blist, attx8);

    void* args[] = {(void*)&ei, (void*)&bcnt, (void*)&need, (void*)&blist,
                    (void*)&attx8, (void*)&b2, (void*)&out, (void*)&deg,
                    (void*)&partials, (void*)&newid, (void*)&emb};
    hipLaunchCooperativeKernel((void*)tail_kernel, dim3(TAIL_GRID), dim3(256),
                               args, 0, stream);
}

// Round 12
// 357.710 us; speedup vs baseline: 1.7827x; 1.7827x over previous
//
#include <hip/hip_runtime.h>
#include <hip/hip_bf16.h>

// Problem constants (fixed by setup_inputs)
#define NG      100
#define NPG     500
#define EPG     4000
#define HID     128
#define NNODES  (NG*NPG)     // 50000
#define NE      (NG*EPG)     // 400000
#define KSEL    2000         // ceil(0.5*4000)
#define NB_SCAN ((NNODES + 255) / 256)   // 196

#define MAXB    1024         // boundary-list capacity per graph (expect ~140)
#define NRC     8            // repair chunks per graph (MAXB/128)
#define RJT     4            // repair j-tiles (512/128); was 8 — see repair hdr
#define DELTA   0.03125f     // screening margin (~2x observed bf16 att max err)

// Output layout (floats, concatenated in reference return order)
#define O_ATT   0
#define O_CEW   (NE)
#define O_SEW   (2*NE)
#define O_MASK  (3*NE)
#define O_CEI   (4*NE)            // 2*NE entries: new_row then new_col
#define O_NMASK (6*NE)            // NNODES entries
#define O_CX    (6*NE + NNODES)   // NNODES*HID entries

typedef __attribute__((ext_vector_type(8))) short  short8;
typedef __attribute__((ext_vector_type(8))) __bf16 bf16x8;
typedef __attribute__((ext_vector_type(4))) float  f32x4;

#define MFMA16(a,b,c) __builtin_amdgcn_mfma_f32_16x16x32_bf16( \
    __builtin_bit_cast(bf16x8,(a)), __builtin_bit_cast(bf16x8,(b)), (c), 0, 0, 0)

#define GLOAD_LDS16(g, l) __builtin_amdgcn_global_load_lds( \
    (const __attribute__((address_space(1))) unsigned int*)(g), \
    (__attribute__((address_space(3)))       unsigned int*)(l), 16, 0, 0)

__device__ __forceinline__ unsigned short tobf(float x) {
    __hip_bfloat16 hb = __float2bfloat16(x);
    return *(unsigned short*)&hb;
}

// ---------------- fused preprocessing ----------------
#define PREP_TOBF 6250
#define PREP_PACK 512
#define PREP_DEG  49
#define PREP_GRID (PREP_TOBF + PREP_PACK + PREP_DEG + 1)

__global__ __launch_bounds__(256)
void prep_kernel(const float* __restrict__ emb, const float* __restrict__ W1,
                 unsigned short* __restrict__ eb, unsigned short* __restrict__ ph,
                 float* __restrict__ deg, int* __restrict__ bcnt)
{
    const int blk = blockIdx.x;
    const int t   = threadIdx.x;
    if (blk < PREP_TOBF) {
        int i = blk * 256 + t;                       // float4 index, 1.6M total
        float4 v = ((const float4*)emb)[i];
        ushort4 h;
        h.x = tobf(v.x); h.y = tobf(v.y); h.z = tobf(v.z); h.w = tobf(v.w);
        ((ushort4*)eb)[i] = h;
    } else if (blk < PREP_TOBF + PREP_PACK) {
        int idx  = (blk - PREP_TOBF) * 256 + t;      // 131072 total
        int i    = idx & 7;
        int lane = (idx >> 3) & 63;
        int g    = idx >> 9;
        int jsub = g & 3;
        int rem  = g >> 2;
        int jo   = rem & 7;
        int kc   = rem >> 3;                         // 0..7
        int j = jo * 64 + jsub * 16 + (lane & 15);
        int k = kc * 32 + (lane >> 4) * 8 + i;
        ph[idx] = tobf(W1[k * 512 + j]);
    } else if (blk < PREP_TOBF + PREP_PACK + PREP_DEG) {
        int i4 = (blk - PREP_TOBF - PREP_PACK) * 256 + t;
        if (i4 < NNODES / 4) ((float4*)deg)[i4] = make_float4(0.f, 0.f, 0.f, 0.f);
    } else {
        if (t < NG) bcnt[t] = 0;
    }
}

// ---------------- screening GEMM: bf16 MFMA, double-buffered B ------------
// v12 == v6 (best measured: 120.2-120.7 us, VGPR 116, MfmaUtil 37%).
// 16 segments of 32 j-cols, 2 x 16 KB LDS buffers, 64 edges/wave (4 mt).
// Evidence: allocator budget ~116 VGPR, never holds A resident (R3/R4/R7);
// min-waves hints spill (R2/R5); mt=2 and K-split variants regress (R8/R9);
// occupancy not the limiter (R8). MFMA floor ~50us; the rest is A-remat
// L2 traffic, un-fixable at HIP source level.
__global__ __launch_bounds__(256)
void att5_kernel(const unsigned short* __restrict__ embb,
                 const unsigned short* __restrict__ w1p,
                 const int* __restrict__ ei,
                 const float* __restrict__ b1,
                 const float* __restrict__ W2,
                 const float* __restrict__ b2,
                 float* __restrict__ out)
{
    // 2 buffers x 16 chunks x 512 bf16; chunk c2 = kc*2 + jsub2, kc in [0,8)
    __shared__ __align__(16) unsigned short ldsB[16384];   // 32 KB

    const int t    = threadIdx.x;
    const int w    = t >> 6;        // wave 0..3
    const int lane = t & 63;
    const int r16  = lane & 15;
    const int quad = lane >> 4;

    const int e_base = blockIdx.x * 256 + w * 64;
    const char* eb = (const char*)embb;

    f32x4 A[4][8];
#pragma unroll
    for (int mt = 0; mt < 4; ++mt) {
        int e = min(e_base + mt * 16 + r16, NE - 1);
        const char* sp = eb + (ei[e] << 8);        // 256 B per node row
        const char* dp = eb + (ei[NE + e] << 8);
#pragma unroll
        for (int k4 = 0; k4 < 4; ++k4) {
            A[mt][k4]     = *(const f32x4*)(sp + k4 * 64 + quad * 16);
            A[mt][k4 + 4] = *(const f32x4*)(dp + k4 * 64 + quad * 16);
        }
    }

    float attP[4][4];
#pragma unroll
    for (int mt = 0; mt < 4; ++mt)
#pragma unroll
        for (int rg = 0; rg < 4; ++rg) attP[mt][rg] = 0.0f;

#define STAGE(s_, buf_)                                                      \
    {                                                                        \
        _Pragma("unroll")                                                    \
        for (int cc = 0; cc < 4; ++cc) {                                     \
            int c2   = w * 4 + cc;                                           \
            int kc   = c2 >> 1;                                              \
            int jsub = ((s_) & 1) * 2 + (c2 & 1);                            \
            int jo   = (s_) >> 1;                                            \
            int g    = (kc * 8 + jo) * 4 + jsub;                             \
            GLOAD_LDS16(w1p + g * 512 + lane * 8,                            \
                        ldsB + (buf_) * 8192 + c2 * 512);                    \
        }                                                                    \
    }

    STAGE(0, 0);
    __syncthreads();

    for (int s = 0; s < 16; ++s) {
        const int cur = s & 1;
        if (s < 15) STAGE(s + 1, cur ^ 1);   // prefetch next segment early

#pragma unroll
        for (int jsub2 = 0; jsub2 < 2; ++jsub2) {
            f32x4 acc[4];   // one jsub at a time: 16 VGPRs
#pragma unroll
            for (int mt = 0; mt < 4; ++mt) acc[mt] = f32x4{};

#pragma unroll
            for (int kc = 0; kc < 8; ++kc) {
                short8 B = *(const short8*)(ldsB + cur * 8192 +
                                            (kc * 2 + jsub2) * 512 + lane * 8);
#pragma unroll
                for (int mt = 0; mt < 4; ++mt)
                    acc[mt] = MFMA16(A[mt][kc], B, acc[mt]);
            }

            const int j = s * 32 + jsub2 * 16 + r16;
            const float b1v = b1[j], w2v = W2[j];
#pragma unroll
            for (int mt = 0; mt < 4; ++mt)
#pragma unroll
                for (int rg = 0; rg < 4; ++rg)
                    attP[mt][rg] += fmaxf(acc[mt][rg] + b1v, 0.0f) * w2v;
        }
        __syncthreads();   // prefetch landed + all reads of cur done
    }
#undef STAGE

#pragma unroll
    for (int mt = 0; mt < 4; ++mt)
#pragma unroll
        for (int rg = 0; rg < 4; ++rg) {
            float v = attP[mt][rg];
#pragma unroll
            for (int msk = 1; msk <= 8; msk <<= 1) v += __shfl_xor(v, msk, 64);
            attP[mt][rg] = v;
        }

    const float bias2 = b2[0];
    if (r16 < 4) {
#pragma unroll
        for (int mt = 0; mt < 4; ++mt) {
            const int row = quad * 4 + r16;    // C/D row = (lane>>4)*4 + reg
            const int e   = e_base + mt * 16 + row;
            if (e < NE) out[O_ATT + e] = attP[mt][r16] + bias2;
        }
    }
}

// ---------------- per-graph top-k screening ----------------
__device__ __forceinline__ unsigned enc_key(float f) {
    unsigned u = __float_as_uint(f);
    return (u & 0x80000000u) ? ~u : (u | 0x80000000u);
}
__device__ __forceinline__ float dec_key(unsigned k) {
    unsigned u = (k & 0x80000000u) ? (k ^ 0x80000000u) : ~k;
    return __uint_as_float(u);
}

__device__ __forceinline__ int wave_sum(int c) {
#pragma unroll
    for (int m = 1; m <= 32; m <<= 1) c += __shfl_xor(c, m, 64);
    return c;
}

__global__ __launch_bounds__(256)
void topk4_kernel(const int* __restrict__ ei, float* __restrict__ out,
                  float* __restrict__ deg, int* __restrict__ bcnt,
                  int* __restrict__ need, int* __restrict__ blist)
{
    __shared__ int cnt;

    const int g  = blockIdx.x;
    const int t  = threadIdx.x;
    const int e0 = g * EPG;
    const int cbase = t * 16;            // blocked chunk, threads 0..249 active
    const bool act = (t < 250);

    unsigned kreg[16];
    if (act) {
#pragma unroll
        for (int q4 = 0; q4 < 4; ++q4) {
            float4 v = *(const float4*)&out[O_ATT + e0 + cbase + q4 * 4];
            kreg[q4 * 4 + 0] = enc_key(v.x);
            kreg[q4 * 4 + 1] = enc_key(v.y);
            kreg[q4 * 4 + 2] = enc_key(v.z);
            kreg[q4 * 4 + 3] = enc_key(v.w);
        }
    }

    unsigned lo = 0u, hi = 0xFFFFFFFFu;
    while (lo < hi) {
        unsigned mid = lo + ((hi - lo) >> 1) + 1u;
        if (t == 0) cnt = 0;
        __syncthreads();
        int c = 0;
        if (act) {
#pragma unroll
            for (int q = 0; q < 16; ++q) c += (kreg[q] >= mid) ? 1 : 0;
        }
        c = wave_sum(c);
        if ((t & 63) == 0 && c) atomicAdd(&cnt, c);
        __syncthreads();
        int f = cnt;
        if (f >= KSEL) lo = mid; else hi = mid - 1u;
        __syncthreads();
    }
    const unsigned K = lo;
    const float v = dec_key(K);
    const unsigned khi = enc_key(v + DELTA);
    const unsigned klo = enc_key(v - DELTA);

    if (t == 0) cnt = 0;
    __syncthreads();
    {
        int c = 0;
        if (act) {
#pragma unroll
            for (int q = 0; q < 16; ++q) c += (kreg[q] > khi) ? 1 : 0;
        }
        c = wave_sum(c);
        if ((t & 63) == 0 && c) atomicAdd(&cnt, c);
    }
    __syncthreads();
    if (t == 0) need[g] = KSEL - cnt;

    if (act) {
#pragma unroll
        for (int q = 0; q < 16; ++q) {
            unsigned kk = kreg[q];
            int ge = e0 + cbase + q;
            float a = dec_key(kk);
            if (kk > khi) {
                out[O_CEW + ge]  = a;
                out[O_SEW + ge]  = 0.0f;
                out[O_MASK + ge] = 1.0f;
                atomicAdd(&deg[ei[ge]], 1.0f);
                atomicAdd(&deg[ei[NE + ge]], 1.0f);
            } else if (kk < klo) {
                out[O_CEW + ge]  = 0.0f;
                out[O_SEW + ge]  = a;
                out[O_MASK + ge] = 0.0f;
            } else {
                int p = atomicAdd(&bcnt[g], 1);
                if (p < MAXB) blist[g * MAXB + p] = ge;
            }
        }
    }
}

// ---------------- exact fp32 recompute of boundary edges ----------------
// v12: RJT 8 -> 4 (j-tile 64 -> 128, acc[8][8]). Attribution from R11's
// coop experiment: tail kernels are only ~10-30us; the ~240us non-att5
// remainder is prep+topk4+repair, and by arithmetic repair (~80-100us,
// LDS/staging-bound) dominates: RJT=8 staged the SAME X tile 8x per
// (g,ch) - 5 GB of Xs LDS reads + 8x redundant global gather. Halving
// j-tiles halves X staging (global + LDS write + LDS read) at constant
// FMA. Live set ~105 VGPR (acc 64 + xv/wv 16 + addr) - under the ~116
// allocator budget, no spill expected (failure signature: WRITE_SIZE
// ballooning). Live-mask (R10) kept: dead te-groups skip gather/FMA.
#define TE_  128
#define PADX 132
#define PADW 132

__global__ __launch_bounds__(256)
void repair_kernel(const float* __restrict__ emb, const int* __restrict__ ei,
                   const float* __restrict__ W1, const float* __restrict__ b1,
                   const float* __restrict__ W2,
                   const int* __restrict__ bcnt, const int* __restrict__ blist,
                   float* __restrict__ attx8)
{
    const int blk = blockIdx.x;
    const int ch  = blk / (NG * RJT);          // 0..NRC-1
    const int rem = blk - ch * (NG * RJT);
    const int g   = rem >> 2;                  // /RJT
    const int jt  = rem & 3;
    const int bc  = min(bcnt[g], MAXB);
    if (ch * 128 >= bc) return;
    const int live = min(bc - ch * 128, TE_);  // 1..128 real edges this chunk

    __shared__ __align__(16) float Xs[32 * PADX];   // 16.9 KB
    __shared__ __align__(16) float Ws[32 * PADW];   // 16.9 KB
    __shared__ int sidx[TE_], cidx[TE_];

    const int t = threadIdx.x;
    if (t < TE_) {
        int lid = ch * 128 + t;
        int lc  = min(lid, bc - 1);
        int e   = blist[g * MAXB + lc];
        sidx[t] = ei[e];
        cidx[t] = ei[NE + e];
    }
    __syncthreads();

    const int te = t & 15;     // edge group: edges te*8..te*8+7
    const int tj = t >> 4;     // j group: j jt*128 + tj*8..+7
    const bool alive = (te * 8 < live);

    float acc[8][8];
#pragma unroll
    for (int a = 0; a < 8; ++a)
#pragma unroll
        for (int b = 0; b < 8; ++b) acc[a][b] = 0.0f;

    for (int kt = 0; kt < 8; ++kt) {
        __syncthreads();
        // stage X: 32 k x live e (gathered), float4 along k; dead columns
        // skipped (their stale data is only read by dead threads)
#pragma unroll
        for (int i = 0; i < 4; ++i) {
            int flat = i * 256 + t;           // 0..1023
            int e  = flat >> 3;
            if (e < live) {
                int k4 = flat & 7;
                int k  = kt * 32 + k4 * 4;
                const float* src;
                if (k < HID) src = emb + (long)sidx[e] * HID + k;
                else         src = emb + (long)cidx[e] * HID + (k - HID);
                float4 v = *(const float4*)src;
                int kl = k4 * 4;
                Xs[(kl + 0) * PADX + e] = v.x;
                Xs[(kl + 1) * PADX + e] = v.y;
                Xs[(kl + 2) * PADX + e] = v.z;
                Xs[(kl + 3) * PADX + e] = v.w;
            }
        }
        // stage W1 tile: 32 k x 128 j (this block's jt slice)
#pragma unroll
        for (int i = 0; i < 4; ++i) {
            int flat = i * 256 + t;           // 0..1023
            int kl = flat >> 5;               // 0..31
            int j4 = flat & 31;               // 0..31 (float4 within 128 j)
            float4 v = *(const float4*)&W1[(kt * 32 + kl) * 512 + jt * 128 + j4 * 4];
            *(float4*)&Ws[kl * PADW + j4 * 4] = v;
        }
        __syncthreads();

        if (alive) {
#pragma unroll 2
            for (int kl = 0; kl < 32; ++kl) {
                float4 xa = *(const float4*)&Xs[kl * PADX + te * 8];
                float4 xb = *(const float4*)&Xs[kl * PADX + te * 8 + 4];
                float4 wa = *(const float4*)&Ws[kl * PADW + tj * 8];
                float4 wb = *(const float4*)&Ws[kl * PADW + tj * 8 + 4];
                float xv[8] = {xa.x, xa.y, xa.z, xa.w, xb.x, xb.y, xb.z, xb.w};
                float wv[8] = {wa.x, wa.y, wa.z, wa.w, wb.x, wb.y, wb.z, wb.w};
#pragma unroll
                for (int a = 0; a < 8; ++a)
#pragma unroll
                    for (int b = 0; b < 8; ++b)
                        acc[a][b] = fmaf(xv[a], wv[b], acc[a][b]);
            }
        }
    }

    // epilogue: relu(+b1) * W2 over this block's 8 j's per thread
    __syncthreads();
    float* red = Xs;   // 16*136 = 2176 floats, fits
    if (alive) {
        const int jb = jt * 128 + tj * 8;
        float4 b1a = *(const float4*)&b1[jb];
        float4 b1b = *(const float4*)&b1[jb + 4];
        float4 w2a = *(const float4*)&W2[jb];
        float4 w2b = *(const float4*)&W2[jb + 4];
        float bv[8] = {b1a.x, b1a.y, b1a.z, b1a.w, b1b.x, b1b.y, b1b.z, b1b.w};
        float wv[8] = {w2a.x, w2a.y, w2a.z, w2a.w, w2b.x, w2b.y, w2b.z, w2b.w};
#pragma unroll
        for (int a = 0; a < 8; ++a) {
            float s = 0.0f;
#pragma unroll
            for (int b = 0; b < 8; ++b)
                s = fmaf(fmaxf(acc[a][b] + bv[b], 0.0f), wv[b], s);
            red[tj * 136 + te * 8 + a] = s;
        }
    }
    __syncthreads();
    if (t < TE_ && t < live) {
        float s = 0.0f;
#pragma unroll
        for (int q = 0; q < 16; ++q) s += red[q * 136 + t];
        attx8[(g * MAXB + ch * 128 + t) * RJT + jt] = s;
    }
}

// ---------------- exact selection among boundary edges ----------------
__global__ __launch_bounds__(256)
void select_kernel(const int* __restrict__ ei, const int* __restrict__ bcnt,
                   const int* __restrict__ need, const int* __restrict__ blist,
                   const float* __restrict__ attx8, const float* __restrict__ b2,
                   float* __restrict__ out, float* __restrict__ deg)
{
    __shared__ float sa[MAXB];
    __shared__ int   si[MAXB];
    const int g = blockIdx.x;
    const int t = threadIdx.x;
    const int b = min(bcnt[g], MAXB);
    const int n = need[g];
    const float bias2 = b2[0];

    for (int i = t; i < b; i += 256) {
        float s = bias2;
#pragma unroll
        for (int jt = 0; jt < RJT; ++jt)
            s += attx8[(g * MAXB + i) * RJT + jt];
        sa[i] = s;
        si[i] = blist[g * MAXB + i];
    }
    __syncthreads();

    for (int i = t; i < b; i += 256) {
        float ai = sa[i];
        int   ii = si[i];
        int rank = 0;
        for (int j = 0; j < b; ++j)
            rank += (sa[j] > ai || (sa[j] == ai && si[j] < ii)) ? 1 : 0;
        bool flag = rank < n;
        out[O_CEW + ii]  = flag ? ai : 0.0f;
        out[O_SEW + ii]  = flag ? 0.0f : ai;
        out[O_MASK + ii] = flag ? 1.0f : 0.0f;
        if (flag) {
            atomicAdd(&deg[ei[ii]], 1.0f);
            atomicAdd(&deg[ei[NE + ii]], 1.0f);
        }
    }
}

// ---------------- node relabel: global prefix scan over node_mask ----------------
__global__ __launch_bounds__(256)
void scanA(const float* __restrict__ deg, int* __restrict__ partials)
{
    __shared__ int s[256];
    int t = threadIdx.x;
    int n = blockIdx.x * 256 + t;
    int m = (n < NNODES && deg[n] > 0.5f) ? 1 : 0;
    s[t] = m;
    __syncthreads();
    for (int off = 128; off > 0; off >>= 1) {
        if (t < off) s[t] += s[t + off];
        __syncthreads();
    }
    if (t == 0) partials[blockIdx.x] = s[0];
}

// scanC with scanB fused: each block reduces partials[0..b) itself
// (196 ints, 8-step tree) - removes the serializing 1-block scanB launch.
__global__ __launch_bounds__(256)
void scanC(float* __restrict__ deg_nm, const int* __restrict__ partials,
           int* __restrict__ newid)
{
    __shared__ int s[256];
    __shared__ int p[256];
    int t = threadIdx.x;
    int b = blockIdx.x;
    int n = b * 256 + t;

    // exclusive prefix for this block: sum of partials[0..b)
    p[t] = (t < NB_SCAN && t < b) ? partials[t] : 0;
    __syncthreads();
    for (int off = 128; off > 0; off >>= 1) {
        if (t < off) p[t] += p[t + off];
        __syncthreads();
    }
    const int ex_b = p[0];
    __syncthreads();

    int m = (n < NNODES && deg_nm[n] > 0.5f) ? 1 : 0;
    s[t] = m;
    __syncthreads();
    for (int off = 1; off < 256; off <<= 1) {
        int x = (t >= off) ? s[t - off] : 0;
        __syncthreads();
        s[t] += x;
        __syncthreads();
    }
    if (n < NNODES) {
        newid[n]  = ex_b + s[t] - 1;          // cumsum(mask)-1
        deg_nm[n] = m ? 1.0f : 0.0f;          // finalize node_mask output
    }
}

// ---------------- fused epilogue: edge relabel + causal_x ----------------
// blocks [0,1563): causal_edge_index; blocks [1563,7813): causal_x float4s
#define FIN_EDGE 1563
#define FIN_GRID (FIN_EDGE + 6250)

__global__ __launch_bounds__(256)
void final_kernel(const float* __restrict__ emb, const int* __restrict__ ei,
                  const int* __restrict__ newid, const float* __restrict__ nm,
                  float* __restrict__ out)
{
    const int blk = blockIdx.x;
    const int t   = threadIdx.x;
    if (blk < FIN_EDGE) {
        int e = blk * 256 + t;
        if (e >= NE) return;
        bool flag = out[O_MASK + e] > 0.5f;
        int row = ei[e];
        int col = ei[NE + e];
        out[O_CEI + e]      = flag ? (float)newid[row] : -1.0f;
        out[O_CEI + NE + e] = flag ? (float)newid[col] : -1.0f;
    } else {
        int i4 = (blk - FIN_EDGE) * 256 + t;           // float4 index
        if (i4 >= NNODES * HID / 4) return;
        int n = i4 >> 5;                               // 32 float4 per node
        float4 v = ((const float4*)emb)[i4];
        if (!(nm[n] > 0.5f)) v = make_float4(0.0f, 0.0f, 0.0f, 0.0f);
        ((float4*)(out + O_CX))[i4] = v;
    }
}

extern "C" void kernel_launch(void* const* d_in, const int* in_sizes, int n_in,
                              void* d_out, int out_size, void* d_ws, size_t ws_size,
                              hipStream_t stream)
{
    const float* emb = (const float*)d_in[0];
    const int*   ei  = (const int*)d_in[1];
    // d_in[2] = node_batch (implied by edge layout; unused)
    const float* W1  = (const float*)d_in[3];
    const float* b1  = (const float*)d_in[4];
    const float* W2  = (const float*)d_in[5];
    const float* b2  = (const float*)d_in[6];
    float* out = (float*)d_out;

    char* wsb = (char*)d_ws;
    int*   newid    = (int*)wsb;                          // 200000 B
    int*   partials = (int*)(wsb + 200704);
    int*   bcnt     = (int*)(wsb + 201728);               // NG ints
    int*   need     = (int*)(wsb + 202752);               // NG ints
    int*   blist    = (int*)(wsb + 203776);               // NG*MAXB ints (400 KB)
    float* attx8    = (float*)(wsb + 203776 + NG*MAXB*4); // NG*MAXB*RJT floats
    unsigned short* embb = (unsigned short*)(wsb + 203776 + NG*MAXB*4 + NG*MAXB*RJT*4);
    unsigned short* w1p  = embb + NNODES * HID;           // 131072 bf16
    float* deg = out + O_NMASK;                           // node_mask region as deg accum

    prep_kernel<<<PREP_GRID, 256, 0, stream>>>(emb, W1, embb, w1p, deg, bcnt);
    att5_kernel<<<(NE + 255) / 256, 256, 0, stream>>>(embb, w1p, ei, b1, W2, b2, out);
    topk4_kernel<<<NG, 256, 0, stream>>>(ei, out, deg, bcnt, need, blist);
    repair_kernel<<<NG * NRC * RJT, 256, 0, stream>>>(emb, ei, W1, b1, W2,
                                                      bcnt, blist, attx8);
    select_kernel<<<NG, 256, 0, stream>>>(ei, bcnt, need, blist, attx8, b2, out, deg);
    scanA<<<NB_SCAN, 256, 0, stream>>>(deg, partials);
    scanC<<<NB_SCAN, 256, 0, stream>>>(deg, partials, newid);
    final_kernel<<<FIN_GRID, 256, 0, stream>>>(emb, ei, newid, deg, out);
}